// Round 9
// baseline (118.543 us; speedup 1.0000x reference)
//
#include <hip/hip_runtime.h>

#define BB 4
#define TT 1024
#define DD 128
#define LL 32   // chunk length
#define CC 32   // TT/LL
#define EPSV 1e-6f

#define BTD (BB*TT*DD)
#define BCD (BB*CC*DD)

// workspace offsets (floats)
#define OFF_QC   0                  // relu(q) -> qc (in-place)
#define OFF_KH   (OFF_QC + BTD)     // relu(k) -> kh (in-place)
#define OFF_V    (OFF_KH + BTD)
#define OFF_G    (OFF_V  + BTD)     // sigmoid(a)
#define OFF_CL   (OFF_G  + BTD)
#define OFF_KS   (OFF_CL + BCD)
#define OFF_Z0   (OFF_KS + BCD)
#define OFF_U    (OFF_Z0 + BCD)     // [B][C][D][D]  (8.4 MB)
#define OFF_S0   (OFF_U  + BB*CC*DD*DD)

// ---------------------------------------------------------------------------
// Kernel 1 (proven, unchanged): fused 4-projection GEMM.
// 1024 blocks (128 row-tiles x 8 mat-halves), 50KB LDS -> 3 blocks/CU.
// ---------------------------------------------------------------------------
__global__ __launch_bounds__(256) void k_gemm(
    const float* __restrict__ x,
    const float* __restrict__ Wq, const float* __restrict__ bq,
    const float* __restrict__ Wk, const float* __restrict__ bk,
    const float* __restrict__ Wv, const float* __restrict__ bv,
    const float* __restrict__ Wa, const float* __restrict__ ba,
    float* __restrict__ ws)
{
    __shared__ float xs [32][DD];
    __shared__ float wsh[64][132];

    const int tid = threadIdx.x;
    const int bx  = blockIdx.x;
    const int rt  = bx >> 3;
    const int mt  = bx & 7;
    const int m   = mt >> 1;
    const int jh  = mt & 1;

    const float* W    = (m==0)?Wq : (m==1)?Wk : (m==2)?Wv : Wa;
    const float* bias = (m==0)?bq : (m==1)?bk : (m==2)?bv : ba;

    {
        const float4* xg = (const float4*)(x + (size_t)rt*32*DD);
        #pragma unroll
        for (int r=0;r<4;r++){
            int f = tid + r*256;
            *(float4*)&xs[f>>5][(f&31)*4] = xg[f];
        }
        const float4* wg = (const float4*)(W + (size_t)jh*64*DD);
        #pragma unroll
        for (int r=0;r<8;r++){
            int f = tid + r*256;
            *(float4*)&wsh[f>>5][(f&31)*4] = wg[f];
        }
    }
    __syncthreads();

    const int ci = tid & 15;
    const int ri = tid >> 4;

    float acc[2][4];
    #pragma unroll
    for (int cc=0;cc<4;cc++){
        float bv_ = bias[jh*64 + ci + 16*cc];
        acc[0][cc]=bv_; acc[1][cc]=bv_;
    }

    #pragma unroll 2
    for (int k4=0; k4<32; k4++){
        float4 xa = *(const float4*)&xs[ri   ][k4*4];
        float4 xb = *(const float4*)&xs[ri+16][k4*4];
        #pragma unroll
        for (int cc=0;cc<4;cc++){
            float4 w = *(const float4*)&wsh[ci+16*cc][k4*4];
            acc[0][cc] = fmaf(xa.x,w.x, fmaf(xa.y,w.y, fmaf(xa.z,w.z, fmaf(xa.w,w.w, acc[0][cc]))));
            acc[1][cc] = fmaf(xb.x,w.x, fmaf(xb.y,w.y, fmaf(xb.z,w.z, fmaf(xb.w,w.w, acc[1][cc]))));
        }
    }

    float* dst = ws + ((m==0)?OFF_QC : (m==1)?OFF_KH : (m==2)?OFF_V : OFF_G);
    #pragma unroll
    for (int rr=0;rr<2;rr++){
        int row = rt*32 + ri + 16*rr;
        #pragma unroll
        for (int cc=0;cc<4;cc++){
            float v = acc[rr][cc];
            if (m==0 || m==1) v = fmaxf(v, 0.f);
            else if (m==3)    v = 1.f/(1.f+__expf(-v));
            dst[(size_t)row*DD + jh*64 + ci + 16*cc] = v;
        }
    }
}

// ---------------------------------------------------------------------------
// Kernel 2: per (chunk, i-quarter) postprocess + U quarter-GEMM.
// Block owns cols/rows [32q, 32q+32): cumprod, qc, kh, kb, cL, Ksum for own
// cols; U rows own quarter x all j (v full width). 512 blocks, 32KB LDS
// -> 5 blocks/CU.
// ---------------------------------------------------------------------------
__global__ __launch_bounds__(256) void k_chunk(float* __restrict__ ws)
{
    __shared__ float qs [LL][32];
    __shared__ float krs[LL][32];
    __shared__ float gs [LL][32];   // sigmoid(a) -> in-place cumprod c
    __shared__ float vs [LL][DD];
    __shared__ float kbs[LL][32];

    const int tid = threadIdx.x;
    const int bq_ = blockIdx.x;        // bc*4 + q
    const int bc  = bq_ >> 2;
    const int iq  = bq_ & 3;
    const int ibase = iq*32;
    const int b   = bc / CC;
    const int t0  = (bc % CC) * LL;
    const size_t tile = (size_t)(b*TT + t0)*DD;

    {   // stage own 32x32 slices of q,k,g (256 f4 each) + v full 32x128
        const int t = tid >> 3, c4 = (tid & 7)*4;
        const size_t off = tile + (size_t)t*DD + ibase + c4;
        *(float4*)&qs [t][c4] = *(const float4*)(ws + OFF_QC + off);
        *(float4*)&krs[t][c4] = *(const float4*)(ws + OFF_KH + off);
        *(float4*)&gs [t][c4] = *(const float4*)(ws + OFF_G  + off);
        #pragma unroll
        for (int r=0;r<4;r++){
            int f = tid + r*256;
            int tv = f >> 5, cv = (f & 31)*4;
            *(float4*)&vs[tv][cv] = *(const float4*)(ws + OFF_V + tile + (size_t)tv*DD + cv);
        }
    }
    __syncthreads();

    if (tid < 32){                     // per-column cumprod; write cL
        float c = 1.f;
        #pragma unroll
        for (int t=0;t<LL;t++){ c *= gs[t][tid]; gs[t][tid] = c; }
        ws[OFF_CL + (size_t)bc*DD + ibase + tid] = c;
    }
    __syncthreads();

    {   // qc, kh, kb (4 t-rows per thread)
        const int col = tid & 31;
        const int tg  = tid >> 5;      // 0..7
        const float cl = gs[LL-1][col];
        #pragma unroll
        for (int r=0;r<4;r++){
            int t = tg*4 + r;
            float cv = gs[t][col];
            ws[OFF_QC + tile + (size_t)t*DD + ibase + col] = qs[t][col] * cv;
            float kh = krs[t][col] / cv;
            ws[OFF_KH + tile + (size_t)t*DD + ibase + col] = kh;
            kbs[t][col] = kh * cl;
        }
    }
    __syncthreads();

    if (tid < 32){                     // Ksum per own column
        float s = 0.f;
        #pragma unroll
        for (int t=0;t<LL;t++) s += kbs[t][tid];
        ws[OFF_KS + (size_t)bc*DD + ibase + tid] = s;
    }

    // U[ibase+il][j] = sum_u kb[u][il]*v[u][j]; thread=(j=tid&127, ih=tid>>7)
    const int j  = tid & 127;
    const int ih = tid >> 7;           // 0/1 -> 16 rows each
    float vr[LL];
    #pragma unroll
    for (int u=0;u<LL;u++) vr[u]=vs[u][j];
    float* Ug = ws + OFF_U + (size_t)bc*DD*DD;
    #pragma unroll
    for (int i4=0;i4<4;i4++){
        int il = ih*16 + i4*4;
        float a0=0.f,a1=0.f,a2=0.f,a3=0.f;
        #pragma unroll
        for (int u=0;u<LL;u++){
            float4 kb4 = *(const float4*)(&kbs[u][il]);   // wave-broadcast
            float vu = vr[u];
            a0 = fmaf(kb4.x,vu,a0); a1 = fmaf(kb4.y,vu,a1);
            a2 = fmaf(kb4.z,vu,a2); a3 = fmaf(kb4.w,vu,a3);
        }
        Ug[(size_t)(ibase+il+0)*DD + j]=a0; Ug[(size_t)(ibase+il+1)*DD + j]=a1;
        Ug[(size_t)(ibase+il+2)*DD + j]=a2; Ug[(size_t)(ibase+il+3)*DD + j]=a3;
    }
}

// ---------------------------------------------------------------------------
// Kernel 3 (proven pattern): per-element scan over CC=32 chunks, 16-deep ring.
// 512 blocks x 128 threads.
// ---------------------------------------------------------------------------
__global__ __launch_bounds__(128) void k_scan(float* __restrict__ ws)
{
    __shared__ float cls[CC], kss[CC];
    const int bi = blockIdx.x;      // b*DD + i
    const int b  = bi >> 7;
    const int i  = bi & 127;
    const int j  = threadIdx.x;

    if (j < CC)        cls[j]      = ws[OFF_CL + (size_t)(b*CC + j)*DD + i];
    else if (j < 2*CC) kss[j - CC] = ws[OFF_KS + (size_t)(b*CC + j - CC)*DD + i];
    __syncthreads();

    const float* U  = ws + OFF_U;
    float*       s0 = ws + OFF_S0;
    float*       z0 = ws + OFF_Z0;
    const size_t base = (size_t)b*CC*DD*DD + (size_t)i*DD + j;

    float up[16];
    #pragma unroll
    for (int p=0;p<16;p++) up[p] = U[base + (size_t)p*DD*DD];

    float s = 0.f, z = 0.f;
    #pragma unroll
    for (int ch=0; ch<CC; ch++){
        s0[base + (size_t)ch*DD*DD] = s;
        if (j==0) z0[(size_t)(b*CC+ch)*DD + i] = z;
        float u  = up[ch & 15];
        if (ch + 16 < CC) up[ch & 15] = U[base + (size_t)(ch+16)*DD*DD];
        float cl = cls[ch];
        s = fmaf(cl, s, u);
        z = fmaf(cl, z, kss[ch]);
    }
}

// ---------------------------------------------------------------------------
// Kernel 4: per (chunk, j-quarter) output. 512 blocks, ~48KB LDS -> 3/CU.
// scores+den per block (full 128-dot); y for own 32-col quarter.
// ---------------------------------------------------------------------------
__global__ __launch_bounds__(256) void k_out(const float* __restrict__ ws, float* __restrict__ y)
{
    __shared__ float qcs[LL][DD+4];
    __shared__ float khs[LL][DD+4];
    __shared__ float vsm[LL][36];
    __shared__ float Ss[LL][LL];
    __shared__ float denS[LL];
    __shared__ float z0s[DD];
    __shared__ float s0s[32][36];

    const int tid = threadIdx.x;
    const int bq_ = blockIdx.x;        // bc*4 + jq
    const int bc  = bq_ >> 2;
    const int jq  = bq_ & 3;
    const int jbase = jq * 32;
    const int b   = bc / CC;
    const int ch  = bc % CC;
    const int t0  = ch * LL;
    const size_t tile = (size_t)(b*TT + t0)*DD;
    const float* s0g = ws + OFF_S0 + (size_t)bc*DD*DD;

    {
        const float4* qcg = (const float4*)(ws + OFF_QC + tile);
        const float4* khg = (const float4*)(ws + OFF_KH + tile);
        #pragma unroll
        for (int rep=0; rep<4; rep++){
            int f = tid + rep*256;     // 1024 f4 each
            int t = f >> 5, k4 = f & 31;
            *(float4*)&qcs[t][k4*4] = qcg[f];
            *(float4*)&khs[t][k4*4] = khg[f];
        }
        {   // v quarter [32][32] = 256 f4
            int t = tid >> 3, c = (tid & 7)*4;
            *(float4*)&vsm[t][c] =
                *(const float4*)(ws + OFF_V + tile + (size_t)t*DD + jbase + c);
        }
        if (tid < DD) z0s[tid] = ws[OFF_Z0 + (size_t)bc*DD + tid];
    }
    __syncthreads();

    // scores S[t][u] = qc_t . kh_u (full 128-dot), masked u<=t
    {
        int t = tid >> 3, ug = tid & 7;
        #pragma unroll
        for (int uu=0; uu<4; uu++){
            int u = ug*4 + uu;
            float s = 0.f;
            #pragma unroll 8
            for (int k4=0; k4<32; k4++){
                float4 q4 = *(const float4*)&qcs[t][k4*4];
                float4 h4 = *(const float4*)&khs[u][k4*4];
                s = fmaf(q4.x,h4.x, fmaf(q4.y,h4.y, fmaf(q4.z,h4.z, fmaf(q4.w,h4.w, s))));
            }
            Ss[t][u] = (u <= t) ? s : 0.f;
        }
    }
    __syncthreads();

    if (tid < LL){
        int t = tid;
        float d = EPSV;
        for (int u=0; u<=t; u++) d += Ss[t][u];
        #pragma unroll 8
        for (int kk=0; kk<DD; kk++) d += qcs[t][kk]*z0s[kk];
        denS[t] = d;
    }

    const int t  = tid >> 3;
    const int jg = tid & 7;
    const int j0 = jg * 4;             // within the 32-col quarter
    float y4[4] = {0.f,0.f,0.f,0.f};

    __syncthreads();
    // intra-chunk: S @ V (quarter)
    #pragma unroll 8
    for (int u=0; u<LL; u++){
        float sv = Ss[t][u];
        float4 v4 = *(const float4*)&vsm[u][j0];
        y4[0]=fmaf(sv,v4.x,y4[0]); y4[1]=fmaf(sv,v4.y,y4[1]);
        y4[2]=fmaf(sv,v4.z,y4[2]); y4[3]=fmaf(sv,v4.w,y4[3]);
    }

    // inter-chunk: qc @ s0 (col-quarter), 4 slices of 32 rows
    for (int sl=0; sl<4; sl++){
        __syncthreads();
        {   // stage slice [32 i][32 j] = 256 f4, coalesced
            int row = tid >> 3, c4 = (tid & 7)*4;
            *(float4*)&s0s[row][c4] =
                *(const float4*)(s0g + (size_t)(sl*32 + row)*DD + jbase + c4);
        }
        __syncthreads();
        #pragma unroll 8
        for (int ii=0; ii<32; ii++){
            float qv = qcs[t][sl*32+ii];
            float4 s4 = *(const float4*)&s0s[ii][j0];
            y4[0]=fmaf(qv,s4.x,y4[0]); y4[1]=fmaf(qv,s4.y,y4[1]);
            y4[2]=fmaf(qv,s4.z,y4[2]); y4[3]=fmaf(qv,s4.w,y4[3]);
        }
    }

    const float rd = 1.f/denS[t];
    float* yg = y + tile + (size_t)t*DD + jbase + j0;
    *(float4*)yg = make_float4(y4[0]*rd, y4[1]*rd, y4[2]*rd, y4[3]*rd);
}

extern "C" void kernel_launch(void* const* d_in, const int* in_sizes, int n_in,
                              void* d_out, int out_size, void* d_ws, size_t ws_size,
                              hipStream_t stream)
{
    const float* x  = (const float*)d_in[0];
    const float* Wq = (const float*)d_in[1]; const float* bq = (const float*)d_in[2];
    const float* Wk = (const float*)d_in[3]; const float* bk = (const float*)d_in[4];
    const float* Wv = (const float*)d_in[5]; const float* bv = (const float*)d_in[6];
    const float* Wa = (const float*)d_in[7]; const float* ba = (const float*)d_in[8];
    float* ws = (float*)d_ws;
    float* yo = (float*)d_out;

    hipLaunchKernelGGL(k_gemm,  dim3(1024),    dim3(256), 0, stream,
                       x, Wq,bq, Wk,bk, Wv,bv, Wa,ba, ws);
    hipLaunchKernelGGL(k_chunk, dim3(BB*CC*4), dim3(256), 0, stream, ws);
    hipLaunchKernelGGL(k_scan,  dim3(BB*DD),   dim3(128), 0, stream, ws);
    hipLaunchKernelGGL(k_out,   dim3(BB*CC*4), dim3(256), 0, stream, ws, yo);
}

// Round 10
// 115.035 us; speedup vs baseline: 1.0305x; 1.0305x over previous
//
#include <hip/hip_runtime.h>

#define BB 4
#define TT 1024
#define DD 128
#define LL 32   // chunk length
#define CC 32   // TT/LL
#define EPSV 1e-6f

#define BTD (BB*TT*DD)
#define BCD (BB*CC*DD)

// workspace offsets (floats)
#define OFF_QC   0                  // relu(q) -> qc (in-place)
#define OFF_KH   (OFF_QC + BTD)     // relu(k) -> kh (in-place)
#define OFF_V    (OFF_KH + BTD)
#define OFF_G    (OFF_V  + BTD)     // sigmoid(a)
#define OFF_CL   (OFF_G  + BTD)
#define OFF_KS   (OFF_CL + BCD)
#define OFF_Z0   (OFF_KS + BCD)
#define OFF_U    (OFF_Z0 + BCD)     // [B][C][D][D]  (8.4 MB)
#define OFF_S0   (OFF_U  + BB*CC*DD*DD)

// ---------------------------------------------------------------------------
// Kernel 1 (proven, unchanged): fused 4-projection GEMM.
// ---------------------------------------------------------------------------
__global__ __launch_bounds__(256) void k_gemm(
    const float* __restrict__ x,
    const float* __restrict__ Wq, const float* __restrict__ bq,
    const float* __restrict__ Wk, const float* __restrict__ bk,
    const float* __restrict__ Wv, const float* __restrict__ bv,
    const float* __restrict__ Wa, const float* __restrict__ ba,
    float* __restrict__ ws)
{
    __shared__ float xs [32][DD];
    __shared__ float wsh[64][132];

    const int tid = threadIdx.x;
    const int bx  = blockIdx.x;
    const int rt  = bx >> 3;
    const int mt  = bx & 7;
    const int m   = mt >> 1;
    const int jh  = mt & 1;

    const float* W    = (m==0)?Wq : (m==1)?Wk : (m==2)?Wv : Wa;
    const float* bias = (m==0)?bq : (m==1)?bk : (m==2)?bv : ba;

    {
        const float4* xg = (const float4*)(x + (size_t)rt*32*DD);
        #pragma unroll
        for (int r=0;r<4;r++){
            int f = tid + r*256;
            *(float4*)&xs[f>>5][(f&31)*4] = xg[f];
        }
        const float4* wg = (const float4*)(W + (size_t)jh*64*DD);
        #pragma unroll
        for (int r=0;r<8;r++){
            int f = tid + r*256;
            *(float4*)&wsh[f>>5][(f&31)*4] = wg[f];
        }
    }
    __syncthreads();

    const int ci = tid & 15;
    const int ri = tid >> 4;

    float acc[2][4];
    #pragma unroll
    for (int cc=0;cc<4;cc++){
        float bv_ = bias[jh*64 + ci + 16*cc];
        acc[0][cc]=bv_; acc[1][cc]=bv_;
    }

    #pragma unroll 2
    for (int k4=0; k4<32; k4++){
        float4 xa = *(const float4*)&xs[ri   ][k4*4];
        float4 xb = *(const float4*)&xs[ri+16][k4*4];
        #pragma unroll
        for (int cc=0;cc<4;cc++){
            float4 w = *(const float4*)&wsh[ci+16*cc][k4*4];
            acc[0][cc] = fmaf(xa.x,w.x, fmaf(xa.y,w.y, fmaf(xa.z,w.z, fmaf(xa.w,w.w, acc[0][cc]))));
            acc[1][cc] = fmaf(xb.x,w.x, fmaf(xb.y,w.y, fmaf(xb.z,w.z, fmaf(xb.w,w.w, acc[1][cc]))));
        }
    }

    float* dst = ws + ((m==0)?OFF_QC : (m==1)?OFF_KH : (m==2)?OFF_V : OFF_G);
    #pragma unroll
    for (int rr=0;rr<2;rr++){
        int row = rt*32 + ri + 16*rr;
        #pragma unroll
        for (int cc=0;cc<4;cc++){
            float v = acc[rr][cc];
            if (m==0 || m==1) v = fmaxf(v, 0.f);
            else if (m==3)    v = 1.f/(1.f+__expf(-v));
            dst[(size_t)row*DD + jh*64 + ci + 16*cc] = v;
        }
    }
}

// ---------------------------------------------------------------------------
// Kernel 2 (proven R9, unchanged): per (chunk, i-quarter) postprocess + U.
// ---------------------------------------------------------------------------
__global__ __launch_bounds__(256) void k_chunk(float* __restrict__ ws)
{
    __shared__ float qs [LL][32];
    __shared__ float krs[LL][32];
    __shared__ float gs [LL][32];
    __shared__ float vs [LL][DD];
    __shared__ float kbs[LL][32];

    const int tid = threadIdx.x;
    const int bq_ = blockIdx.x;        // bc*4 + q
    const int bc  = bq_ >> 2;
    const int iq  = bq_ & 3;
    const int ibase = iq*32;
    const int b   = bc / CC;
    const int t0  = (bc % CC) * LL;
    const size_t tile = (size_t)(b*TT + t0)*DD;

    {
        const int t = tid >> 3, c4 = (tid & 7)*4;
        const size_t off = tile + (size_t)t*DD + ibase + c4;
        *(float4*)&qs [t][c4] = *(const float4*)(ws + OFF_QC + off);
        *(float4*)&krs[t][c4] = *(const float4*)(ws + OFF_KH + off);
        *(float4*)&gs [t][c4] = *(const float4*)(ws + OFF_G  + off);
        #pragma unroll
        for (int r=0;r<4;r++){
            int f = tid + r*256;
            int tv = f >> 5, cv = (f & 31)*4;
            *(float4*)&vs[tv][cv] = *(const float4*)(ws + OFF_V + tile + (size_t)tv*DD + cv);
        }
    }
    __syncthreads();

    if (tid < 32){
        float c = 1.f;
        #pragma unroll
        for (int t=0;t<LL;t++){ c *= gs[t][tid]; gs[t][tid] = c; }
        ws[OFF_CL + (size_t)bc*DD + ibase + tid] = c;
    }
    __syncthreads();

    {
        const int col = tid & 31;
        const int tg  = tid >> 5;
        const float cl = gs[LL-1][col];
        #pragma unroll
        for (int r=0;r<4;r++){
            int t = tg*4 + r;
            float cv = gs[t][col];
            ws[OFF_QC + tile + (size_t)t*DD + ibase + col] = qs[t][col] * cv;
            float kh = krs[t][col] / cv;
            ws[OFF_KH + tile + (size_t)t*DD + ibase + col] = kh;
            kbs[t][col] = kh * cl;
        }
    }
    __syncthreads();

    if (tid < 32){
        float s = 0.f;
        #pragma unroll
        for (int t=0;t<LL;t++) s += kbs[t][tid];
        ws[OFF_KS + (size_t)bc*DD + ibase + tid] = s;
    }

    const int j  = tid & 127;
    const int ih = tid >> 7;
    float vr[LL];
    #pragma unroll
    for (int u=0;u<LL;u++) vr[u]=vs[u][j];
    float* Ug = ws + OFF_U + (size_t)bc*DD*DD;
    #pragma unroll
    for (int i4=0;i4<4;i4++){
        int il = ih*16 + i4*4;
        float a0=0.f,a1=0.f,a2=0.f,a3=0.f;
        #pragma unroll
        for (int u=0;u<LL;u++){
            float4 kb4 = *(const float4*)(&kbs[u][il]);
            float vu = vr[u];
            a0 = fmaf(kb4.x,vu,a0); a1 = fmaf(kb4.y,vu,a1);
            a2 = fmaf(kb4.z,vu,a2); a3 = fmaf(kb4.w,vu,a3);
        }
        Ug[(size_t)(ibase+il+0)*DD + j]=a0; Ug[(size_t)(ibase+il+1)*DD + j]=a1;
        Ug[(size_t)(ibase+il+2)*DD + j]=a2; Ug[(size_t)(ibase+il+3)*DD + j]=a3;
    }
}

// ---------------------------------------------------------------------------
// Kernel 3 (proven R9, unchanged): per-element scan, CC=32, 16-deep ring.
// ---------------------------------------------------------------------------
__global__ __launch_bounds__(128) void k_scan(float* __restrict__ ws)
{
    __shared__ float cls[CC], kss[CC];
    const int bi = blockIdx.x;
    const int b  = bi >> 7;
    const int i  = bi & 127;
    const int j  = threadIdx.x;

    if (j < CC)        cls[j]      = ws[OFF_CL + (size_t)(b*CC + j)*DD + i];
    else if (j < 2*CC) kss[j - CC] = ws[OFF_KS + (size_t)(b*CC + j - CC)*DD + i];
    __syncthreads();

    const float* U  = ws + OFF_U;
    float*       s0 = ws + OFF_S0;
    float*       z0 = ws + OFF_Z0;
    const size_t base = (size_t)b*CC*DD*DD + (size_t)i*DD + j;

    float up[16];
    #pragma unroll
    for (int p=0;p<16;p++) up[p] = U[base + (size_t)p*DD*DD];

    float s = 0.f, z = 0.f;
    #pragma unroll
    for (int ch=0; ch<CC; ch++){
        s0[base + (size_t)ch*DD*DD] = s;
        if (j==0) z0[(size_t)(b*CC+ch)*DD + i] = z;
        float u  = up[ch & 15];
        if (ch + 16 < CC) up[ch & 15] = U[base + (size_t)(ch+16)*DD*DD];
        float cl = cls[ch];
        s = fmaf(cl, s, u);
        z = fmaf(cl, z, kss[ch]);
    }
}

// ---------------------------------------------------------------------------
// Kernel 4: per (chunk, t-half, j-half) output. 512 blocks, ~45KB LDS
// -> 2 blocks/CU resident. Scores split across t (16t x 32u per block,
// 2x redundancy across j-halves only); y for own 16t x 64j.
// ---------------------------------------------------------------------------
__global__ __launch_bounds__(256) void k_out(const float* __restrict__ ws, float* __restrict__ y)
{
    __shared__ float khs[LL][DD+4];     // all u rows (scores)       16.9 KB
    __shared__ float qcs[16][DD+4];     // own t rows                 8.4 KB
    __shared__ float vsm[LL][68];       // all u rows x own j-half    8.7 KB
    __shared__ float s0s[32][68];       // staged s0 slice            8.7 KB
    __shared__ float Ss[16][LL];        //                            2.0 KB
    __shared__ float denS[16];
    __shared__ float z0s[DD];

    const int tid = threadIdx.x;
    const int blk = blockIdx.x;        // bc*4 + th*2 + jh
    const int bc  = blk >> 2;
    const int th  = (blk >> 1) & 1;
    const int jh  = blk & 1;
    const int tbase = th * 16;
    const int jbase = jh * 64;
    const int b   = bc / CC;
    const int ch  = bc % CC;
    const int t0  = ch * LL;
    const size_t tile = (size_t)(b*TT + t0)*DD;
    const float* s0g = ws + OFF_S0 + (size_t)bc*DD*DD;

    {   // kh full 32x128 (1024 f4), qc own 16x128 (512 f4), v 32x64 (512 f4)
        const float4* khg = (const float4*)(ws + OFF_KH + tile);
        #pragma unroll
        for (int r=0;r<4;r++){
            int f = tid + r*256;
            int t = f >> 5, k4 = f & 31;
            *(float4*)&khs[t][k4*4] = khg[f];
        }
        const float4* qcg = (const float4*)(ws + OFF_QC + tile + (size_t)tbase*DD);
        #pragma unroll
        for (int r=0;r<2;r++){
            int f = tid + r*256;
            int t = f >> 5, k4 = f & 31;
            *(float4*)&qcs[t][k4*4] = qcg[f];
        }
        #pragma unroll
        for (int r=0;r<2;r++){
            int f = tid + r*256;
            int t = f >> 4, c = (f & 15)*4;
            *(float4*)&vsm[t][c] =
                *(const float4*)(ws + OFF_V + tile + (size_t)t*DD + jbase + c);
        }
        if (tid < DD) z0s[tid] = ws[OFF_Z0 + (size_t)bc*DD + tid];
    }
    __syncthreads();

    // scores: thread owns (tl = tid>>4, u = 2*(tid&15), +1); mask u<=tbase+tl
    {
        const int tl = tid >> 4;
        const int tg = tbase + tl;
        #pragma unroll
        for (int uu=0; uu<2; uu++){
            int u = (tid & 15)*2 + uu;
            float s = 0.f;
            #pragma unroll 8
            for (int k4=0; k4<32; k4++){
                float4 q4 = *(const float4*)&qcs[tl][k4*4];
                float4 h4 = *(const float4*)&khs[u][k4*4];
                s = fmaf(q4.x,h4.x, fmaf(q4.y,h4.y, fmaf(q4.z,h4.z, fmaf(q4.w,h4.w, s))));
            }
            Ss[tl][u] = (u <= tg) ? s : 0.f;
        }
    }
    __syncthreads();

    if (tid < 16){
        int tl = tid;
        float d = EPSV;
        #pragma unroll
        for (int u=0; u<LL; u++) d += Ss[tl][u];   // masked entries are 0
        #pragma unroll 8
        for (int kk=0; kk<DD; kk++) d += qcs[tl][kk]*z0s[kk];
        denS[tl] = d;
    }

    const int tl = tid >> 4;
    const int j0 = (tid & 15) * 4;     // within the 64-col half
    float y4[4] = {0.f,0.f,0.f,0.f};

    __syncthreads();
    // intra-chunk: S @ V (own j-half)
    #pragma unroll 8
    for (int u=0; u<LL; u++){
        float sv = Ss[tl][u];
        float4 v4 = *(const float4*)&vsm[u][j0];
        y4[0]=fmaf(sv,v4.x,y4[0]); y4[1]=fmaf(sv,v4.y,y4[1]);
        y4[2]=fmaf(sv,v4.z,y4[2]); y4[3]=fmaf(sv,v4.w,y4[3]);
    }

    // inter-chunk: qc @ s0 (own j-half), 4 slices of 32 i-rows
    for (int sl=0; sl<4; sl++){
        __syncthreads();
        #pragma unroll
        for (int r=0;r<2;r++){
            int f = tid + r*256;
            int row = f >> 4, c4 = (f & 15)*4;
            *(float4*)&s0s[row][c4] =
                *(const float4*)(s0g + (size_t)(sl*32 + row)*DD + jbase + c4);
        }
        __syncthreads();
        #pragma unroll 8
        for (int ii=0; ii<32; ii++){
            float qv = qcs[tl][sl*32+ii];
            float4 s4 = *(const float4*)&s0s[ii][j0];
            y4[0]=fmaf(qv,s4.x,y4[0]); y4[1]=fmaf(qv,s4.y,y4[1]);
            y4[2]=fmaf(qv,s4.z,y4[2]); y4[3]=fmaf(qv,s4.w,y4[3]);
        }
    }

    const float rd = 1.f/denS[tl];
    float* yg = y + tile + (size_t)(tbase + tl)*DD + jbase + j0;
    *(float4*)yg = make_float4(y4[0]*rd, y4[1]*rd, y4[2]*rd, y4[3]*rd);
}

extern "C" void kernel_launch(void* const* d_in, const int* in_sizes, int n_in,
                              void* d_out, int out_size, void* d_ws, size_t ws_size,
                              hipStream_t stream)
{
    const float* x  = (const float*)d_in[0];
    const float* Wq = (const float*)d_in[1]; const float* bq = (const float*)d_in[2];
    const float* Wk = (const float*)d_in[3]; const float* bk = (const float*)d_in[4];
    const float* Wv = (const float*)d_in[5]; const float* bv = (const float*)d_in[6];
    const float* Wa = (const float*)d_in[7]; const float* ba = (const float*)d_in[8];
    float* ws = (float*)d_ws;
    float* yo = (float*)d_out;

    hipLaunchKernelGGL(k_gemm,  dim3(1024),    dim3(256), 0, stream,
                       x, Wq,bq, Wk,bk, Wv,bv, Wa,ba, ws);
    hipLaunchKernelGGL(k_chunk, dim3(BB*CC*4), dim3(256), 0, stream, ws);
    hipLaunchKernelGGL(k_scan,  dim3(BB*DD),   dim3(128), 0, stream, ws);
    hipLaunchKernelGGL(k_out,   dim3(BB*CC*4), dim3(256), 0, stream, ws, yo);
}

// Round 11
// 113.621 us; speedup vs baseline: 1.0433x; 1.0124x over previous
//
#include <hip/hip_runtime.h>

#define BB 4
#define TT 1024
#define DD 128
#define LL 32   // chunk length
#define CC 32   // TT/LL
#define EPSV 1e-6f

#define BTD (BB*TT*DD)
#define BCD (BB*CC*DD)

// workspace offsets (floats)
#define OFF_QC   0                  // relu(q) -> qc (in-place)
#define OFF_KH   (OFF_QC + BTD)     // relu(k) -> kh (in-place)
#define OFF_V    (OFF_KH + BTD)
#define OFF_G    (OFF_V  + BTD)     // sigmoid(a)
#define OFF_CL   (OFF_G  + BTD)
#define OFF_KS   (OFF_CL + BCD)
#define OFF_Z0   (OFF_KS + BCD)
#define OFF_U    (OFF_Z0 + BCD)     // [B][C][D][D]  (8.4 MB)
#define OFF_S0   (OFF_U  + BB*CC*DD*DD)

// ---------------------------------------------------------------------------
// Kernel 1 v2: fused 4-projection GEMM, 64x64 tile, 4x4 acc/thread.
// 512 blocks (64 row-tiles x 8 mat-halves), 65.8KB LDS -> 2 blocks/CU.
// LDS bytes/fma: 2 (was 3) — k_gemm was LDS-read-bound.
// ---------------------------------------------------------------------------
__global__ __launch_bounds__(256) void k_gemm(
    const float* __restrict__ x,
    const float* __restrict__ Wq, const float* __restrict__ bq,
    const float* __restrict__ Wk, const float* __restrict__ bk,
    const float* __restrict__ Wv, const float* __restrict__ bv,
    const float* __restrict__ Wa, const float* __restrict__ ba,
    float* __restrict__ ws)
{
    __shared__ float xs [64][DD];      // 32 KB
    __shared__ float wsh[64][132];     // 33.8 KB

    const int tid = threadIdx.x;
    const int bx  = blockIdx.x;
    const int rt  = bx >> 3;           // row-tile 0..63 (64 rows each)
    const int mt  = bx & 7;
    const int m   = mt >> 1;           // matrix 0:q 1:k 2:v 3:a
    const int jh  = mt & 1;            // column half

    const float* W    = (m==0)?Wq : (m==1)?Wk : (m==2)?Wv : Wa;
    const float* bias = (m==0)?bq : (m==1)?bk : (m==2)?bv : ba;

    {
        const float4* xg = (const float4*)(x + (size_t)rt*64*DD);
        const float4* wg = (const float4*)(W + (size_t)jh*64*DD);
        #pragma unroll
        for (int r=0;r<8;r++){
            int f = tid + r*256;       // 2048 f4 each
            *(float4*)&xs [f>>5][(f&31)*4] = xg[f];
            *(float4*)&wsh[f>>5][(f&31)*4] = wg[f];
        }
    }
    __syncthreads();

    const int ci = tid & 15;           // cols ci + 16*cc
    const int ri = tid >> 4;           // rows ri + 16*rr

    float acc[4][4];
    #pragma unroll
    for (int cc=0;cc<4;cc++){
        float bv_ = bias[jh*64 + ci + 16*cc];
        #pragma unroll
        for (int rr=0;rr<4;rr++) acc[rr][cc]=bv_;
    }

    #pragma unroll 2
    for (int k4=0; k4<32; k4++){
        float4 xa0 = *(const float4*)&xs[ri     ][k4*4];
        float4 xa1 = *(const float4*)&xs[ri + 16][k4*4];
        float4 xa2 = *(const float4*)&xs[ri + 32][k4*4];
        float4 xa3 = *(const float4*)&xs[ri + 48][k4*4];
        #pragma unroll
        for (int cc=0;cc<4;cc++){
            float4 w = *(const float4*)&wsh[ci+16*cc][k4*4];
            acc[0][cc] = fmaf(xa0.x,w.x, fmaf(xa0.y,w.y, fmaf(xa0.z,w.z, fmaf(xa0.w,w.w, acc[0][cc]))));
            acc[1][cc] = fmaf(xa1.x,w.x, fmaf(xa1.y,w.y, fmaf(xa1.z,w.z, fmaf(xa1.w,w.w, acc[1][cc]))));
            acc[2][cc] = fmaf(xa2.x,w.x, fmaf(xa2.y,w.y, fmaf(xa2.z,w.z, fmaf(xa2.w,w.w, acc[2][cc]))));
            acc[3][cc] = fmaf(xa3.x,w.x, fmaf(xa3.y,w.y, fmaf(xa3.z,w.z, fmaf(xa3.w,w.w, acc[3][cc]))));
        }
    }

    float* dst = ws + ((m==0)?OFF_QC : (m==1)?OFF_KH : (m==2)?OFF_V : OFF_G);
    #pragma unroll
    for (int rr=0;rr<4;rr++){
        int row = rt*64 + ri + 16*rr;
        #pragma unroll
        for (int cc=0;cc<4;cc++){
            float v = acc[rr][cc];
            if (m==0 || m==1) v = fmaxf(v, 0.f);
            else if (m==3)    v = 1.f/(1.f+__expf(-v));
            dst[(size_t)row*DD + jh*64 + ci + 16*cc] = v;
        }
    }
}

// ---------------------------------------------------------------------------
// Kernel 2 (proven R10, unchanged): per (chunk, i-quarter) postprocess + U.
// ---------------------------------------------------------------------------
__global__ __launch_bounds__(256) void k_chunk(float* __restrict__ ws)
{
    __shared__ float qs [LL][32];
    __shared__ float krs[LL][32];
    __shared__ float gs [LL][32];
    __shared__ float vs [LL][DD];
    __shared__ float kbs[LL][32];

    const int tid = threadIdx.x;
    const int bq_ = blockIdx.x;        // bc*4 + q
    const int bc  = bq_ >> 2;
    const int iq  = bq_ & 3;
    const int ibase = iq*32;
    const int b   = bc / CC;
    const int t0  = (bc % CC) * LL;
    const size_t tile = (size_t)(b*TT + t0)*DD;

    {
        const int t = tid >> 3, c4 = (tid & 7)*4;
        const size_t off = tile + (size_t)t*DD + ibase + c4;
        *(float4*)&qs [t][c4] = *(const float4*)(ws + OFF_QC + off);
        *(float4*)&krs[t][c4] = *(const float4*)(ws + OFF_KH + off);
        *(float4*)&gs [t][c4] = *(const float4*)(ws + OFF_G  + off);
        #pragma unroll
        for (int r=0;r<4;r++){
            int f = tid + r*256;
            int tv = f >> 5, cv = (f & 31)*4;
            *(float4*)&vs[tv][cv] = *(const float4*)(ws + OFF_V + tile + (size_t)tv*DD + cv);
        }
    }
    __syncthreads();

    if (tid < 32){
        float c = 1.f;
        #pragma unroll
        for (int t=0;t<LL;t++){ c *= gs[t][tid]; gs[t][tid] = c; }
        ws[OFF_CL + (size_t)bc*DD + ibase + tid] = c;
    }
    __syncthreads();

    {
        const int col = tid & 31;
        const int tg  = tid >> 5;
        const float cl = gs[LL-1][col];
        #pragma unroll
        for (int r=0;r<4;r++){
            int t = tg*4 + r;
            float cv = gs[t][col];
            ws[OFF_QC + tile + (size_t)t*DD + ibase + col] = qs[t][col] * cv;
            float kh = krs[t][col] / cv;
            ws[OFF_KH + tile + (size_t)t*DD + ibase + col] = kh;
            kbs[t][col] = kh * cl;
        }
    }
    __syncthreads();

    if (tid < 32){
        float s = 0.f;
        #pragma unroll
        for (int t=0;t<LL;t++) s += kbs[t][tid];
        ws[OFF_KS + (size_t)bc*DD + ibase + tid] = s;
    }

    const int j  = tid & 127;
    const int ih = tid >> 7;
    float vr[LL];
    #pragma unroll
    for (int u=0;u<LL;u++) vr[u]=vs[u][j];
    float* Ug = ws + OFF_U + (size_t)bc*DD*DD;
    #pragma unroll
    for (int i4=0;i4<4;i4++){
        int il = ih*16 + i4*4;
        float a0=0.f,a1=0.f,a2=0.f,a3=0.f;
        #pragma unroll
        for (int u=0;u<LL;u++){
            float4 kb4 = *(const float4*)(&kbs[u][il]);
            float vu = vr[u];
            a0 = fmaf(kb4.x,vu,a0); a1 = fmaf(kb4.y,vu,a1);
            a2 = fmaf(kb4.z,vu,a2); a3 = fmaf(kb4.w,vu,a3);
        }
        Ug[(size_t)(ibase+il+0)*DD + j]=a0; Ug[(size_t)(ibase+il+1)*DD + j]=a1;
        Ug[(size_t)(ibase+il+2)*DD + j]=a2; Ug[(size_t)(ibase+il+3)*DD + j]=a3;
    }
}

// ---------------------------------------------------------------------------
// Kernel 3 (proven R10, unchanged): per-element scan, CC=32, 16-deep ring.
// ---------------------------------------------------------------------------
__global__ __launch_bounds__(128) void k_scan(float* __restrict__ ws)
{
    __shared__ float cls[CC], kss[CC];
    const int bi = blockIdx.x;
    const int b  = bi >> 7;
    const int i  = bi & 127;
    const int j  = threadIdx.x;

    if (j < CC)        cls[j]      = ws[OFF_CL + (size_t)(b*CC + j)*DD + i];
    else if (j < 2*CC) kss[j - CC] = ws[OFF_KS + (size_t)(b*CC + j - CC)*DD + i];
    __syncthreads();

    const float* U  = ws + OFF_U;
    float*       s0 = ws + OFF_S0;
    float*       z0 = ws + OFF_Z0;
    const size_t base = (size_t)b*CC*DD*DD + (size_t)i*DD + j;

    float up[16];
    #pragma unroll
    for (int p=0;p<16;p++) up[p] = U[base + (size_t)p*DD*DD];

    float s = 0.f, z = 0.f;
    #pragma unroll
    for (int ch=0; ch<CC; ch++){
        s0[base + (size_t)ch*DD*DD] = s;
        if (j==0) z0[(size_t)(b*CC+ch)*DD + i] = z;
        float u  = up[ch & 15];
        if (ch + 16 < CC) up[ch & 15] = U[base + (size_t)(ch+16)*DD*DD];
        float cl = cls[ch];
        s = fmaf(cl, s, u);
        z = fmaf(cl, z, kss[ch]);
    }
}

// ---------------------------------------------------------------------------
// Kernel 4 (proven R10, unchanged): per (chunk, t-half, j-half) output.
// ---------------------------------------------------------------------------
__global__ __launch_bounds__(256) void k_out(const float* __restrict__ ws, float* __restrict__ y)
{
    __shared__ float khs[LL][DD+4];
    __shared__ float qcs[16][DD+4];
    __shared__ float vsm[LL][68];
    __shared__ float s0s[32][68];
    __shared__ float Ss[16][LL];
    __shared__ float denS[16];
    __shared__ float z0s[DD];

    const int tid = threadIdx.x;
    const int blk = blockIdx.x;        // bc*4 + th*2 + jh
    const int bc  = blk >> 2;
    const int th  = (blk >> 1) & 1;
    const int jh  = blk & 1;
    const int tbase = th * 16;
    const int jbase = jh * 64;
    const int b   = bc / CC;
    const int ch  = bc % CC;
    const int t0  = ch * LL;
    const size_t tile = (size_t)(b*TT + t0)*DD;
    const float* s0g = ws + OFF_S0 + (size_t)bc*DD*DD;

    {
        const float4* khg = (const float4*)(ws + OFF_KH + tile);
        #pragma unroll
        for (int r=0;r<4;r++){
            int f = tid + r*256;
            int t = f >> 5, k4 = f & 31;
            *(float4*)&khs[t][k4*4] = khg[f];
        }
        const float4* qcg = (const float4*)(ws + OFF_QC + tile + (size_t)tbase*DD);
        #pragma unroll
        for (int r=0;r<2;r++){
            int f = tid + r*256;
            int t = f >> 5, k4 = f & 31;
            *(float4*)&qcs[t][k4*4] = qcg[f];
        }
        #pragma unroll
        for (int r=0;r<2;r++){
            int f = tid + r*256;
            int t = f >> 4, c = (f & 15)*4;
            *(float4*)&vsm[t][c] =
                *(const float4*)(ws + OFF_V + tile + (size_t)t*DD + jbase + c);
        }
        if (tid < DD) z0s[tid] = ws[OFF_Z0 + (size_t)bc*DD + tid];
    }
    __syncthreads();

    {
        const int tl = tid >> 4;
        const int tg = tbase + tl;
        #pragma unroll
        for (int uu=0; uu<2; uu++){
            int u = (tid & 15)*2 + uu;
            float s = 0.f;
            #pragma unroll 8
            for (int k4=0; k4<32; k4++){
                float4 q4 = *(const float4*)&qcs[tl][k4*4];
                float4 h4 = *(const float4*)&khs[u][k4*4];
                s = fmaf(q4.x,h4.x, fmaf(q4.y,h4.y, fmaf(q4.z,h4.z, fmaf(q4.w,h4.w, s))));
            }
            Ss[tl][u] = (u <= tg) ? s : 0.f;
        }
    }
    __syncthreads();

    if (tid < 16){
        int tl = tid;
        float d = EPSV;
        #pragma unroll
        for (int u=0; u<LL; u++) d += Ss[tl][u];
        #pragma unroll 8
        for (int kk=0; kk<DD; kk++) d += qcs[tl][kk]*z0s[kk];
        denS[tl] = d;
    }

    const int tl = tid >> 4;
    const int j0 = (tid & 15) * 4;
    float y4[4] = {0.f,0.f,0.f,0.f};

    __syncthreads();
    #pragma unroll 8
    for (int u=0; u<LL; u++){
        float sv = Ss[tl][u];
        float4 v4 = *(const float4*)&vsm[u][j0];
        y4[0]=fmaf(sv,v4.x,y4[0]); y4[1]=fmaf(sv,v4.y,y4[1]);
        y4[2]=fmaf(sv,v4.z,y4[2]); y4[3]=fmaf(sv,v4.w,y4[3]);
    }

    for (int sl=0; sl<4; sl++){
        __syncthreads();
        #pragma unroll
        for (int r=0;r<2;r++){
            int f = tid + r*256;
            int row = f >> 4, c4 = (f & 15)*4;
            *(float4*)&s0s[row][c4] =
                *(const float4*)(s0g + (size_t)(sl*32 + row)*DD + jbase + c4);
        }
        __syncthreads();
        #pragma unroll 8
        for (int ii=0; ii<32; ii++){
            float qv = qcs[tl][sl*32+ii];
            float4 s4 = *(const float4*)&s0s[ii][j0];
            y4[0]=fmaf(qv,s4.x,y4[0]); y4[1]=fmaf(qv,s4.y,y4[1]);
            y4[2]=fmaf(qv,s4.z,y4[2]); y4[3]=fmaf(qv,s4.w,y4[3]);
        }
    }

    const float rd = 1.f/denS[tl];
    float* yg = y + tile + (size_t)(tbase + tl)*DD + jbase + j0;
    *(float4*)yg = make_float4(y4[0]*rd, y4[1]*rd, y4[2]*rd, y4[3]*rd);
}

extern "C" void kernel_launch(void* const* d_in, const int* in_sizes, int n_in,
                              void* d_out, int out_size, void* d_ws, size_t ws_size,
                              hipStream_t stream)
{
    const float* x  = (const float*)d_in[0];
    const float* Wq = (const float*)d_in[1]; const float* bq = (const float*)d_in[2];
    const float* Wk = (const float*)d_in[3]; const float* bk = (const float*)d_in[4];
    const float* Wv = (const float*)d_in[5]; const float* bv = (const float*)d_in[6];
    const float* Wa = (const float*)d_in[7]; const float* ba = (const float*)d_in[8];
    float* ws = (float*)d_ws;
    float* yo = (float*)d_out;

    hipLaunchKernelGGL(k_gemm,  dim3(512),     dim3(256), 0, stream,
                       x, Wq,bq, Wk,bk, Wv,bv, Wa,ba, ws);
    hipLaunchKernelGGL(k_chunk, dim3(BB*CC*4), dim3(256), 0, stream, ws);
    hipLaunchKernelGGL(k_scan,  dim3(BB*DD),   dim3(128), 0, stream, ws);
    hipLaunchKernelGGL(k_out,   dim3(BB*CC*4), dim3(256), 0, stream, ws, yo);
}